// Round 6
// baseline (2302.908 us; speedup 1.0000x reference)
//
#include <hip/hip_runtime.h>
#include <math.h>

#define NB 1024
#define ND 512
#define ND2 1024
#define NSTEPS 8
#define NSTACK 16
#define NK 1024
#define NV 32000
#define FEPS 1e-6f

typedef _Float16 f16;
typedef f16 f16x8 __attribute__((ext_vector_type(8)));
typedef f16 f16x4 __attribute__((ext_vector_type(4)));
typedef float f32x4 __attribute__((ext_vector_type(4)));

// ---------------- block reduction helpers (blockDim == 256) ----------------
__device__ __forceinline__ float blk_sum(float v, float* red) {
    int t = threadIdx.x;
    red[t] = v; __syncthreads();
    for (int s = 128; s > 0; s >>= 1) {
        if (t < s) red[t] += red[t + s];
        __syncthreads();
    }
    float r = red[0]; __syncthreads();
    return r;
}

__device__ __forceinline__ float blk_max(float v, float* red) {
    int t = threadIdx.x;
    red[t] = v; __syncthreads();
    for (int s = 128; s > 0; s >>= 1) {
        if (t < s) red[t] = fmaxf(red[t], red[t + s]);
        __syncthreads();
    }
    float r = red[0]; __syncthreads();
    return r;
}

__device__ __forceinline__ void split_write(float v, f16* oh, f16* ol, size_t idx) {
    f16 h = (f16)v;
    oh[idx] = h;
    ol[idx] = (f16)((v - (float)h) * 1024.f);
}

// ---------------- init ----------------
__global__ __launch_bounds__(256)
void k_init(float* ptrb, float* remainb, float* scal) {
    int i = blockIdx.x * 256 + threadIdx.x;
    if (i < NB) {
        remainb[i] = 1.f;
        for (int s = 0; s < NSTACK; ++s) ptrb[i * NSTACK + s] = (s == 0) ? 1.f : 0.f;
    }
    if (i < 8) scal[i] = 0.f;
}

__global__ __launch_bounds__(256)
void k_embed(const int* __restrict__ ids, const float* __restrict__ mag,
             const float* __restrict__ ph, f16* __restrict__ zh, f16* __restrict__ zl) {
    int b = blockIdx.x;
    int id = ids[b];
    for (int d = threadIdx.x; d < ND; d += 256) {
        float m = mag[(size_t)id * ND + d];
        float p = ph[(size_t)id * ND + d];
        split_write(m * cosf(p), zh, zl, (size_t)b * ND2 + d);
        split_write(m * sinf(p), zh, zl, (size_t)b * ND2 + ND + d);
    }
}

__global__ __launch_bounds__(256)
void k_cbnorm(const float* __restrict__ cb, float* __restrict__ cbn) {
    __shared__ float red[256];
    int k = blockIdx.x;
    float s = 0.f;
    for (int c = threadIdx.x; c < ND2; c += 256) {
        float v = cb[(size_t)k * ND2 + c];
        s += v * v;
    }
    float tot = blk_sum(s, red);
    if (threadIdx.x == 0) cbn[k] = tot;
}

// ---------------- weight builders ----------------
__global__ __launch_bounds__(256)
void k_buildW1(const float* __restrict__ lr, const float* __restrict__ li,
               f16* __restrict__ oh, f16* __restrict__ ol) {
    int idx = blockIdx.x * 256 + threadIdx.x;
    int n = idx >> 10, k = idx & 1023;
    float v;
    if (n < 512) v = (k < 512) ? lr[n * 512 + k] : -li[n * 512 + (k - 512)];
    else { int n2 = n - 512; v = (k < 512) ? li[n2 * 512 + k] : lr[n2 * 512 + (k - 512)]; }
    split_write(v, oh, ol, idx);
}

__global__ __launch_bounds__(256)
void k_buildWqkv(const float* __restrict__ qr, const float* __restrict__ qi,
                 const float* __restrict__ kr, const float* __restrict__ ki,
                 const float* __restrict__ vr, const float* __restrict__ vi,
                 f16* __restrict__ oh, f16* __restrict__ ol) {
    int idx = blockIdx.x * 256 + threadIdx.x;
    int n = idx >> 10, k = idx & 1023;
    int g = n >> 10, n1 = n & 1023;
    const float* Wr = (g == 0) ? qr : (g == 1) ? kr : vr;
    const float* Wi = (g == 0) ? qi : (g == 1) ? ki : vi;
    float v;
    if (n1 < 512) v = (k < 512) ? Wr[n1 * 512 + k] : -Wi[n1 * 512 + (k - 512)];
    else { int n2 = n1 - 512; v = (k < 512) ? Wi[n2 * 512 + k] : Wr[n2 * 512 + (k - 512)]; }
    split_write(v, oh, ol, idx);
}

__global__ __launch_bounds__(256)
void k_splitcb(const float* __restrict__ in, f16* __restrict__ oh, f16* __restrict__ ol) {
    int idx = blockIdx.x * 256 + threadIdx.x;
    split_write(in[idx], oh, ol, idx);
}

__global__ __launch_bounds__(256)
void k_split_h(const float* __restrict__ in, f16* __restrict__ oh, size_t n) {
    size_t i = (size_t)blockIdx.x * 256 + threadIdx.x;
    size_t st = (size_t)gridDim.x * 256;
    for (; i < n; i += st) oh[i] = (f16)in[i];
}

__global__ __launch_bounds__(256)
void k_split1(const float* __restrict__ in, f16* __restrict__ oh, f16* __restrict__ ol) {
    int idx = blockIdx.x * 256 + threadIdx.x;
    split_write(in[idx], oh, ol, idx);
}

// ---------------- in-loop fp16(x2-split) MFMA NT GEMM, in-block split-K-2 ----
// C[M,N] = alpha * (A .* B^T). value = hi + lo/1024, 3-product compensated.
// 512 thr = 2 K-groups x 4 waves (32x32 tiles over 64x64 block). K must be 1024.
// A (hi,lo) staged in LDS (XOR-swizzle, double-buffered); B fragments read
// DIRECTLY FROM GLOBAL (L2) with 2-iteration register prefetch -> LDS traffic
// halves (the binding pipe). n-major XCD-chunked block swizzle for L2 locality.
#define LDW 40
template<int EPI>
__global__ __launch_bounds__(512, 4)
void k_sgemm4(const f16* __restrict__ Ah, const f16* __restrict__ Al,
              const f16* __restrict__ Bh, const f16* __restrict__ Bl,
              float* __restrict__ Cf,
              f16* __restrict__ qh, f16* __restrict__ ql,
              f16* __restrict__ kh, f16* __restrict__ kl,
              f16* __restrict__ vTh, f16* __restrict__ vTl,
              int N, int K, float alpha) {
    __shared__ f16 lds[2][2][2][64 * LDW];   // [buf][group][Ah,Al]  (40 KB)
    const int tid = threadIdx.x;
    const int g = tid >> 8;
    const int gt = tid & 255;
    const int srow = gt >> 2, scb = gt & 3;
    const int sphys = ((scb ^ (srow & 3)) * 8);
    const int lane = tid & 63;
    const int q = (tid >> 6) & 3;
    const int qr = (q >> 1) * 32, qc = (q & 1) * 32;
    const int fr = lane & 15, cbk = lane >> 4;
    // XCD-chunked swizzle, n-major within chunk (gx*gy always % 8 == 0 here)
    const int gx = gridDim.x, gy = gridDim.y;
    const int total = gx * gy;
    const int lin = blockIdx.y * gx + blockIdx.x;
    const int ord = (lin & 7) * (total >> 3) + (lin >> 3);
    const int m0 = (ord % gy) * 64;
    const int n0 = (ord / gy) * 64;
    const int kbase = g * (K >> 1);
    const int iters = K >> 6;                // 16 for K=1024

    const f16* pA  = Ah + (size_t)(m0 + srow) * K + kbase + scb * 8;
    const f16* pAl_ = Al + (size_t)(m0 + srow) * K + kbase + scb * 8;
    const f16* pBh0 = Bh + (size_t)(n0 + qc + fr) * K + kbase + cbk * 8;
    const f16* pBh1 = pBh0 + (size_t)16 * K;
    const f16* pBl0 = Bl + (size_t)(n0 + qc + fr) * K + kbase + cbk * 8;
    const f16* pBl1 = pBl0 + (size_t)16 * K;

    f32x4 z4 = {0.f, 0.f, 0.f, 0.f};
    f32x4 acc0[2][2] = {{z4, z4}, {z4, z4}};
    f32x4 acc1[2][2] = {{z4, z4}, {z4, z4}};

    // prologue: stage A it0 -> buf0; prefetch A it1; load B sets for it0, it1
    f16x8 sa  = *(const f16x8*)pA;
    f16x8 sal = *(const f16x8*)pAl_;
    *(f16x8*)&lds[0][g][0][srow * LDW + sphys] = sa;
    *(f16x8*)&lds[0][g][1][srow * LDW + sphys] = sal;
    sa  = *(const f16x8*)(pA + 32);
    sal = *(const f16x8*)(pAl_ + 32);
    f16x8 b0h0 = *(const f16x8*)pBh0, b0h1 = *(const f16x8*)pBh1;
    f16x8 b0l0 = *(const f16x8*)pBl0, b0l1 = *(const f16x8*)pBl1;
    f16x8 b1h0 = *(const f16x8*)(pBh0 + 32), b1h1 = *(const f16x8*)(pBh1 + 32);
    f16x8 b1l0 = *(const f16x8*)(pBl0 + 32), b1l1 = *(const f16x8*)(pBl1 + 32);
    __syncthreads();

    for (int it = 0; it < iters; it += 2) {
        // ---- even iter: buf0, B-set 0 ----
        {
            f16x8 ah[2], al[2];
            #pragma unroll
            for (int i = 0; i < 2; ++i) {
                int ra = qr + i * 16 + fr;
                int oa = ra * LDW + ((cbk ^ (ra & 3)) * 8);
                ah[i] = *(const f16x8*)&lds[0][g][0][oa];
                al[i] = *(const f16x8*)&lds[0][g][1][oa];
            }
            // stage it+1 -> buf1, prefetch A for it+2
            *(f16x8*)&lds[1][g][0][srow * LDW + sphys] = sa;
            *(f16x8*)&lds[1][g][1][srow * LDW + sphys] = sal;
            if (it + 2 < iters) {
                int ko = (it + 2) * 32;
                sa  = *(const f16x8*)(pA + ko);
                sal = *(const f16x8*)(pAl_ + ko);
            }
            acc0[0][0] = __builtin_amdgcn_mfma_f32_16x16x32_f16(ah[0], b0h0, acc0[0][0], 0, 0, 0);
            acc0[0][1] = __builtin_amdgcn_mfma_f32_16x16x32_f16(ah[0], b0h1, acc0[0][1], 0, 0, 0);
            acc0[1][0] = __builtin_amdgcn_mfma_f32_16x16x32_f16(ah[1], b0h0, acc0[1][0], 0, 0, 0);
            acc0[1][1] = __builtin_amdgcn_mfma_f32_16x16x32_f16(ah[1], b0h1, acc0[1][1], 0, 0, 0);
            acc1[0][0] = __builtin_amdgcn_mfma_f32_16x16x32_f16(ah[0], b0l0, acc1[0][0], 0, 0, 0);
            acc1[0][1] = __builtin_amdgcn_mfma_f32_16x16x32_f16(ah[0], b0l1, acc1[0][1], 0, 0, 0);
            acc1[1][0] = __builtin_amdgcn_mfma_f32_16x16x32_f16(ah[1], b0l0, acc1[1][0], 0, 0, 0);
            acc1[1][1] = __builtin_amdgcn_mfma_f32_16x16x32_f16(ah[1], b0l1, acc1[1][1], 0, 0, 0);
            acc1[0][0] = __builtin_amdgcn_mfma_f32_16x16x32_f16(al[0], b0h0, acc1[0][0], 0, 0, 0);
            acc1[0][1] = __builtin_amdgcn_mfma_f32_16x16x32_f16(al[0], b0h1, acc1[0][1], 0, 0, 0);
            acc1[1][0] = __builtin_amdgcn_mfma_f32_16x16x32_f16(al[1], b0h0, acc1[1][0], 0, 0, 0);
            acc1[1][1] = __builtin_amdgcn_mfma_f32_16x16x32_f16(al[1], b0h1, acc1[1][1], 0, 0, 0);
            if (it + 2 < iters) {
                int ko = (it + 2) * 32;
                b0h0 = *(const f16x8*)(pBh0 + ko); b0h1 = *(const f16x8*)(pBh1 + ko);
                b0l0 = *(const f16x8*)(pBl0 + ko); b0l1 = *(const f16x8*)(pBl1 + ko);
            }
            __syncthreads();
        }
        // ---- odd iter: buf1, B-set 1 ----
        {
            f16x8 ah[2], al[2];
            #pragma unroll
            for (int i = 0; i < 2; ++i) {
                int ra = qr + i * 16 + fr;
                int oa = ra * LDW + ((cbk ^ (ra & 3)) * 8);
                ah[i] = *(const f16x8*)&lds[1][g][0][oa];
                al[i] = *(const f16x8*)&lds[1][g][1][oa];
            }
            if (it + 2 < iters) {
                *(f16x8*)&lds[0][g][0][srow * LDW + sphys] = sa;
                *(f16x8*)&lds[0][g][1][srow * LDW + sphys] = sal;
                if (it + 3 < iters) {
                    int ko = (it + 3) * 32;
                    sa  = *(const f16x8*)(pA + ko);
                    sal = *(const f16x8*)(pAl_ + ko);
                }
            }
            acc0[0][0] = __builtin_amdgcn_mfma_f32_16x16x32_f16(ah[0], b1h0, acc0[0][0], 0, 0, 0);
            acc0[0][1] = __builtin_amdgcn_mfma_f32_16x16x32_f16(ah[0], b1h1, acc0[0][1], 0, 0, 0);
            acc0[1][0] = __builtin_amdgcn_mfma_f32_16x16x32_f16(ah[1], b1h0, acc0[1][0], 0, 0, 0);
            acc0[1][1] = __builtin_amdgcn_mfma_f32_16x16x32_f16(ah[1], b1h1, acc0[1][1], 0, 0, 0);
            acc1[0][0] = __builtin_amdgcn_mfma_f32_16x16x32_f16(ah[0], b1l0, acc1[0][0], 0, 0, 0);
            acc1[0][1] = __builtin_amdgcn_mfma_f32_16x16x32_f16(ah[0], b1l1, acc1[0][1], 0, 0, 0);
            acc1[1][0] = __builtin_amdgcn_mfma_f32_16x16x32_f16(ah[1], b1l0, acc1[1][0], 0, 0, 0);
            acc1[1][1] = __builtin_amdgcn_mfma_f32_16x16x32_f16(ah[1], b1l1, acc1[1][1], 0, 0, 0);
            acc1[0][0] = __builtin_amdgcn_mfma_f32_16x16x32_f16(al[0], b1h0, acc1[0][0], 0, 0, 0);
            acc1[0][1] = __builtin_amdgcn_mfma_f32_16x16x32_f16(al[0], b1h1, acc1[0][1], 0, 0, 0);
            acc1[1][0] = __builtin_amdgcn_mfma_f32_16x16x32_f16(al[1], b1h0, acc1[1][0], 0, 0, 0);
            acc1[1][1] = __builtin_amdgcn_mfma_f32_16x16x32_f16(al[1], b1h1, acc1[1][1], 0, 0, 0);
            if (it + 3 < iters) {
                int ko = (it + 3) * 32;
                b1h0 = *(const f16x8*)(pBh0 + ko); b1h1 = *(const f16x8*)(pBh1 + ko);
                b1l0 = *(const f16x8*)(pBl0 + ko); b1l1 = *(const f16x8*)(pBl1 + ko);
            }
            __syncthreads();
        }
    }

    float val[2][2][4];
    #pragma unroll
    for (int i = 0; i < 2; ++i)
        #pragma unroll
        for (int j = 0; j < 2; ++j)
            #pragma unroll
            for (int jj = 0; jj < 4; ++jj)
                val[i][j][jj] = acc0[i][j][jj] + acc1[i][j][jj] * 9.765625e-4f;

    float* red = (float*)&lds[0][0][0][0];   // 4 waves x 32x33 f32 = 16.9 KB
    if (g == 1) {
        #pragma unroll
        for (int i = 0; i < 2; ++i)
            #pragma unroll
            for (int j = 0; j < 2; ++j) {
                int r = i * 16 + (lane >> 4) * 4, c = j * 16 + (lane & 15);
                #pragma unroll
                for (int jj = 0; jj < 4; ++jj)
                    red[q * 1056 + (r + jj) * 33 + c] = val[i][j][jj];
            }
    }
    __syncthreads();
    if (g == 0) {
        #pragma unroll
        for (int i = 0; i < 2; ++i)
            #pragma unroll
            for (int j = 0; j < 2; ++j) {
                int r = i * 16 + (lane >> 4) * 4, c = j * 16 + (lane & 15);
                #pragma unroll
                for (int jj = 0; jj < 4; ++jj)
                    val[i][j][jj] += red[q * 1056 + (r + jj) * 33 + c];
                int orow = m0 + qr + r;
                int ocol = n0 + qc + c;
                if constexpr (EPI == 0) {
                    #pragma unroll
                    for (int jj = 0; jj < 4; ++jj)
                        Cf[(size_t)(orow + jj) * N + ocol] = alpha * val[i][j][jj];
                } else {
                    int sec = ocol >> 10, lc = ocol & 1023;
                    if (sec == 0) {
                        #pragma unroll
                        for (int jj = 0; jj < 4; ++jj)
                            split_write(val[i][j][jj], qh, ql, (size_t)(orow + jj) * ND2 + lc);
                    } else if (sec == 1) {
                        #pragma unroll
                        for (int jj = 0; jj < 4; ++jj)
                            split_write(val[i][j][jj], kh, kl, (size_t)(orow + jj) * ND2 + lc);
                    } else {
                        f16x4 th, tl;
                        #pragma unroll
                        for (int jj = 0; jj < 4; ++jj) {
                            float v = val[i][j][jj];
                            f16 h = (f16)v;
                            th[jj] = h;
                            tl[jj] = (f16)((v - (float)h) * 1024.f);
                        }
                        *(f16x4*)&vTh[(size_t)lc * ND2 + orow] = th;
                        *(f16x4*)&vTl[(size_t)lc * ND2 + orow] = tl;
                    }
                }
            }
    }
}

// ---------------- decoder GEMM: C = A .* B^T + bias, hi-only fp16 ----------
// BM=256 (A in LDS, XOR-swizzle, dbuf), BN=64 (B = dec_W frags from global/L2,
// 2-iter reg prefetch). 512 thr = 8 waves (4M x 2N), wave tile 64x32, K=1024.
// Grid 2000 blocks, bijective XCD-chunked swizzle (2000 % 8 == 0).
__global__ __launch_bounds__(512, 4)
void k_dgemm4(const f16* __restrict__ A, const f16* __restrict__ B,
              float* __restrict__ C, const float* __restrict__ bias) {
    __shared__ f16 sA[2][256 * LDW];          // 40 KB
    const int bid = blockIdx.x;               // 0..1999
    const int l2 = (bid & 7) * 250 + (bid >> 3);
    const int m0 = (l2 & 3) * 256;
    const int n0 = (l2 >> 2) * 64;
    const int tid = threadIdx.x;
    const int lane = tid & 63, w = tid >> 6;
    const int wr = (w >> 1) * 64, wc = (w & 1) * 32;
    const int fr = lane & 15, cbk = lane >> 4;
    const int K = ND2;
    const int srow = tid >> 1, ca0 = (tid & 1) * 2;

    const f16* pA = A + (size_t)(m0 + srow) * K + ca0 * 8;
    const f16* pB0 = B + (size_t)(n0 + wc + fr) * K + cbk * 8;
    const f16* pB1 = pB0 + (size_t)16 * K;

    f32x4 z4 = {0.f, 0.f, 0.f, 0.f};
    f32x4 acc[4][2] = {{z4, z4}, {z4, z4}, {z4, z4}, {z4, z4}};

    // prologue
    f16x8 sa0 = *(const f16x8*)pA;
    f16x8 sa1 = *(const f16x8*)(pA + 8);
    *(f16x8*)&sA[0][srow * LDW + (((ca0)     ^ (srow & 3)) * 8)] = sa0;
    *(f16x8*)&sA[0][srow * LDW + (((ca0 + 1) ^ (srow & 3)) * 8)] = sa1;
    sa0 = *(const f16x8*)(pA + 32);
    sa1 = *(const f16x8*)(pA + 40);
    f16x8 bE0 = *(const f16x8*)pB0,        bE1 = *(const f16x8*)pB1;
    f16x8 bO0 = *(const f16x8*)(pB0 + 32), bO1 = *(const f16x8*)(pB1 + 32);
    __syncthreads();

    for (int it = 0; it < 32; it += 2) {
        // even: sA[0], bE
        {
            f16x8 a[4];
            #pragma unroll
            for (int i = 0; i < 4; ++i) {
                int ra = wr + i * 16 + fr;
                a[i] = *(const f16x8*)&sA[0][ra * LDW + ((cbk ^ (ra & 3)) * 8)];
            }
            *(f16x8*)&sA[1][srow * LDW + (((ca0)     ^ (srow & 3)) * 8)] = sa0;
            *(f16x8*)&sA[1][srow * LDW + (((ca0 + 1) ^ (srow & 3)) * 8)] = sa1;
            if (it + 2 < 32) {
                int ko = (it + 2) * 32;
                sa0 = *(const f16x8*)(pA + ko);
                sa1 = *(const f16x8*)(pA + ko + 8);
            }
            #pragma unroll
            for (int i = 0; i < 4; ++i) {
                acc[i][0] = __builtin_amdgcn_mfma_f32_16x16x32_f16(a[i], bE0, acc[i][0], 0, 0, 0);
                acc[i][1] = __builtin_amdgcn_mfma_f32_16x16x32_f16(a[i], bE1, acc[i][1], 0, 0, 0);
            }
            if (it + 2 < 32) {
                int ko = (it + 2) * 32;
                bE0 = *(const f16x8*)(pB0 + ko);
                bE1 = *(const f16x8*)(pB1 + ko);
            }
            __syncthreads();
        }
        // odd: sA[1], bO
        {
            f16x8 a[4];
            #pragma unroll
            for (int i = 0; i < 4; ++i) {
                int ra = wr + i * 16 + fr;
                a[i] = *(const f16x8*)&sA[1][ra * LDW + ((cbk ^ (ra & 3)) * 8)];
            }
            if (it + 2 < 32) {
                *(f16x8*)&sA[0][srow * LDW + (((ca0)     ^ (srow & 3)) * 8)] = sa0;
                *(f16x8*)&sA[0][srow * LDW + (((ca0 + 1) ^ (srow & 3)) * 8)] = sa1;
                if (it + 3 < 32) {
                    int ko = (it + 3) * 32;
                    sa0 = *(const f16x8*)(pA + ko);
                    sa1 = *(const f16x8*)(pA + ko + 8);
                }
            }
            #pragma unroll
            for (int i = 0; i < 4; ++i) {
                acc[i][0] = __builtin_amdgcn_mfma_f32_16x16x32_f16(a[i], bO0, acc[i][0], 0, 0, 0);
                acc[i][1] = __builtin_amdgcn_mfma_f32_16x16x32_f16(a[i], bO1, acc[i][1], 0, 0, 0);
            }
            if (it + 3 < 32) {
                int ko = (it + 3) * 32;
                bO0 = *(const f16x8*)(pB0 + ko);
                bO1 = *(const f16x8*)(pB1 + ko);
            }
            __syncthreads();
        }
    }
    #pragma unroll
    for (int i = 0; i < 4; ++i)
        #pragma unroll
        for (int j = 0; j < 2; ++j) {
            int orow = m0 + wr + i * 16 + (lane >> 4) * 4;
            int ocol = n0 + wc + j * 16 + (lane & 15);
            float bv = bias[ocol];
            #pragma unroll
            for (int jj = 0; jj < 4; ++jj)
                C[(size_t)(orow + jj) * NV + ocol] = acc[i][j][jj] + bv;
        }
}

// ---------------- cnorm + modrelu: read f32 p rows, write split fp16 -------
__global__ __launch_bounds__(256)
void k_cnorm(const float* __restrict__ p, f16* __restrict__ ph, f16* __restrict__ pl,
             const float* __restrict__ scale, const float* __restrict__ shift,
             const float* __restrict__ mbias) {
    __shared__ float red[256];
    int b = blockIdx.x, t = threadIdx.x;
    float xr[2], xi[2], hv[2];
    float lsum = 0.f;
    #pragma unroll
    for (int l = 0; l < 2; ++l) {
        int d = t + l * 256;
        float a = p[(size_t)b * ND2 + d], c = p[(size_t)b * ND2 + ND + d];
        xr[l] = a; xi[l] = c;
        float h = sqrtf(a * a + c * c);
        hv[l] = h;
        lsum += h + FEPS;
    }
    float mean = blk_sum(lsum, red) * (1.f / ND);
    float lvar = 0.f;
    #pragma unroll
    for (int l = 0; l < 2; ++l) {
        float dv = (hv[l] + FEPS) - mean;
        lvar += dv * dv;
    }
    float var = blk_sum(lvar, red) * (1.f / (ND - 1));
    float istd = 1.f / sqrtf(var + FEPS);
    #pragma unroll
    for (int l = 0; l < 2; ++l) {
        int d = t + l * 256;
        float nm = ((hv[l] + FEPS) - mean) * istd * scale[d] + shift[d];
        float cc, ss;
        if (hv[l] > 0.f) { cc = xr[l] / hv[l]; ss = xi[l] / hv[l]; }
        else             { cc = 1.f; ss = 0.f; }
        float vr_ = nm * cc, vi_ = nm * ss;
        float n = sqrtf(vr_ * vr_ + vi_ * vi_) + FEPS;
        float aarg = n + mbias[d];
        float sg = (aarg > 0.f ? aarg : 0.f) / n;
        split_write(vr_ * sg, ph, pl, (size_t)b * ND2 + d);
        split_write(vi_ * sg, ph, pl, (size_t)b * ND2 + ND + d);
    }
}

// ---------------- row softmax over 1024, writes scaled (x1024) split fp16
__global__ __launch_bounds__(256)
void k_softmax(const float* __restrict__ S, f16* __restrict__ Ah, f16* __restrict__ Al) {
    __shared__ float red[256];
    int row = blockIdx.x, t = threadIdx.x;
    float v[4];
    float lm = -INFINITY;
    #pragma unroll
    for (int l = 0; l < 4; ++l) {
        v[l] = S[(size_t)row * NB + t + l * 256];
        lm = fmaxf(lm, v[l]);
    }
    float mx = blk_max(lm, red);
    float ls = 0.f;
    #pragma unroll
    for (int l = 0; l < 4; ++l) { v[l] = expf(v[l] - mx); ls += v[l]; }
    float tot = blk_sum(ls, red);
    float inv = 1024.f / tot;
    #pragma unroll
    for (int l = 0; l < 4; ++l)
        split_write(v[l] * inv, Ah, Al, (size_t)row * NB + t + l * 256);
}

// ---------------- halt/ctrl/stack/read/cf
__global__ __launch_bounds__(256)
void k_stack(const float* __restrict__ zf, const float* __restrict__ hW,
             const float* __restrict__ hB, const float* __restrict__ cW,
             const float* __restrict__ cB, float* __restrict__ ptrb,
             float* __restrict__ memb, float* __restrict__ haltb,
             float* __restrict__ cf, f16* __restrict__ cfh, f16* __restrict__ cfl) {
    __shared__ float zfs[ND2];
    __shared__ float red[256];
    __shared__ float pt[NSTACK], npv[NSTACK], wmv[NSTACK];
    __shared__ float snorm;
    int b = blockIdx.x, t = threadIdx.x;
    for (int c = t; c < ND2; c += 256) zfs[c] = zf[(size_t)b * ND2 + c];
    __syncthreads();
    float dh = 0, d0 = 0, d1 = 0, d2 = 0;
    for (int c = t; c < ND2; c += 256) {
        float z = zfs[c];
        dh += z * hW[c];
        d0 += z * cW[c];
        d1 += z * cW[ND2 + c];
        d2 += z * cW[2 * ND2 + c];
    }
    dh = blk_sum(dh, red);
    d0 = blk_sum(d0, red);
    d1 = blk_sum(d1, red);
    d2 = blk_sum(d2, red);
    float h = 1.f / (1.f + expf(-(dh + hB[0])));
    float l0 = d0 + cB[0], l1 = d1 + cB[1], l2 = d2 + cB[2];
    float mx = fmaxf(l0, fmaxf(l1, l2));
    float e0 = expf(l0 - mx), e1 = expf(l1 - mx), e2 = expf(l2 - mx);
    float es = e0 + e1 + e2;
    float push = e0 / es, pop = e1 / es, noop = e2 / es;
    if (t < NSTACK) pt[t] = ptrb[b * NSTACK + t];
    __syncthreads();
    if (t < NSTACK) {
        float up = pt[(t + NSTACK - 1) & 15];
        float dn = pt[(t + 1) & 15];
        npv[t] = push * up + pop * dn + noop * pt[t];
        wmv[t] = push * up;
    }
    __syncthreads();
    if (t == 0) {
        float s = 0.f;
        for (int j = 0; j < NSTACK; ++j) s += npv[j];
        snorm = 1.f / (s + FEPS);
    }
    __syncthreads();
    if (t < NSTACK) {
        npv[t] *= snorm;
        ptrb[b * NSTACK + t] = npv[t];
    }
    __syncthreads();
    for (int c = t; c < ND2; c += 256) {
        float z = zfs[c];
        float rd = 0.f;
        #pragma unroll
        for (int s = 0; s < NSTACK; ++s) {
            size_t off = ((size_t)b * NSTACK + s) * ND2 + c;
            float m = memb[off];
            m = wmv[s] * z + m * (1.f - wmv[s]);
            memb[off] = m;
            rd += m * npv[s];
        }
        float v = z + rd;
        cf[(size_t)b * ND2 + c] = v;
        split_write(v, cfh, cfl, (size_t)b * ND2 + c);
    }
    if (t == 0) haltb[b] = h;
}

// ---------------- VQ argmin + losses + state update
__global__ __launch_bounds__(256)
void k_vqstep(const float* __restrict__ G, const float* __restrict__ cf,
              const float* __restrict__ cb, const float* __restrict__ cbn,
              const f16* __restrict__ cbh, const f16* __restrict__ cbl,
              const float* __restrict__ adj, const float* __restrict__ haltb,
              float* __restrict__ remainb, f16* __restrict__ zh, f16* __restrict__ zl,
              float* __restrict__ zw, int* __restrict__ prev, float* __restrict__ scal,
              int step, int islast) {
    __shared__ float sval[256];
    __shared__ int sidx[256];
    __shared__ float red[256];
    int b = blockIdx.x, t = threadIdx.x;
    float bv = INFINITY; int bi = NK;
    for (int k = t; k < NK; k += 256) {
        float v = cbn[k] - 2.f * G[(size_t)b * NK + k];
        if (v < bv) { bv = v; bi = k; }
    }
    sval[t] = bv; sidx[t] = bi;
    __syncthreads();
    for (int s = 128; s > 0; s >>= 1) {
        if (t < s) {
            float ov = sval[t + s]; int oi = sidx[t + s];
            if (ov < sval[t] || (ov == sval[t] && oi < sidx[t])) { sval[t] = ov; sidx[t] = oi; }
        }
        __syncthreads();
    }
    int sym = sidx[0];
    float sd = 0.f;
    for (int c = t; c < ND2; c += 256) {
        float dd = cb[(size_t)sym * ND2 + c] - cf[(size_t)b * ND2 + c];
        sd += dd * dd;
    }
    float sdt = blk_sum(sd, red);
    float contrib = 0.f;
    if (step > 0) {
        int pv = prev[b];
        float lm = -INFINITY;
        for (int c = t; c < NK; c += 256) lm = fmaxf(lm, adj[(size_t)pv * NK + c]);
        float mxa = blk_max(lm, red);
        float le = 0.f;
        for (int c = t; c < NK; c += 256) le += expf(adj[(size_t)pv * NK + c] - mxa);
        float se = blk_sum(le, red);
        contrib = (mxa + logf(se)) - adj[(size_t)pv * NK + sym];
    }
    float hb = haltb[b];
    float rm = remainb[b];
    float w = islast ? rm : hb * rm;
    for (int c = t; c < ND2; c += 256) {
        zw[(size_t)b * ND2 + c] += w * cb[(size_t)sym * ND2 + c];
        zh[(size_t)b * ND2 + c] = cbh[(size_t)sym * ND2 + c];
        zl[(size_t)b * ND2 + c] = cbl[(size_t)sym * ND2 + c];
    }
    if (t == 0) {
        float nrm = rm * (1.f - hb);
        remainb[b] = nrm;
        atomicAdd(&scal[0], sdt);
        if (step > 0) atomicAdd(&scal[1], contrib);
        atomicAdd(&scal[2], nrm);
        prev[b] = sym;
    }
}

__global__ void k_aux(const float* __restrict__ scal, float* __restrict__ out) {
    out[0] = 1.25f * scal[0] / (1024.f * 1024.f)
           + 0.005f * (scal[1] / 1024.f)
           + 0.0001f * (scal[2] / 1024.f);
}

// ---------------- launch ----------------
extern "C" void kernel_launch(void* const* d_in, const int* in_sizes, int n_in,
                              void* d_out, int out_size, void* d_ws, size_t ws_size,
                              hipStream_t stream) {
    const int*   input_ids  = (const int*)  d_in[0];
    const float* emb_mag    = (const float*)d_in[1];
    const float* emb_phase  = (const float*)d_in[2];
    const float* lin_r      = (const float*)d_in[3];
    const float* lin_i      = (const float*)d_in[4];
    const float* norm_scale = (const float*)d_in[5];
    const float* norm_shift = (const float*)d_in[6];
    const float* mod_bias   = (const float*)d_in[7];
    const float* halt_W     = (const float*)d_in[8];
    const float* halt_b     = (const float*)d_in[9];
    const float* ctrl_W     = (const float*)d_in[10];
    const float* ctrl_b     = (const float*)d_in[11];
    const float* q_r        = (const float*)d_in[12];
    const float* q_i        = (const float*)d_in[13];
    const float* k_r        = (const float*)d_in[14];
    const float* k_i        = (const float*)d_in[15];
    const float* v_r        = (const float*)d_in[16];
    const float* v_i        = (const float*)d_in[17];
    const float* codebook   = (const float*)d_in[18];
    const float* adjacency  = (const float*)d_in[19];
    const float* dec_W      = (const float*)d_in[20];
    const float* dec_b      = (const float*)d_in[21];
    float* out = (float*)d_out;

    // ---- workspace carve-up (f32 region, then f16 region) ----
    float* fb = (float*)d_ws;
    size_t o = 0;
    auto af = [&](size_t n) { float* p = fb + o; o += n; return p; };
    float* scr      = af((size_t)NB * ND2);   // p / S / zf / G (time-aliased)
    float* cf       = af((size_t)NB * ND2);
    float* memb     = af((size_t)NB * NSTACK * ND2);
    float* zw       = af((size_t)NB * ND2);
    float* ptrb     = af((size_t)NB * NSTACK);
    float* haltb    = af(NB);
    float* remainb  = af(NB);
    float* cbn      = af(NK);
    int*   prev     = (int*)af(NB);
    float* scal     = af(8);

    f16* hbuf = (f16*)(fb + o);
    size_t ho = 0;
    auto ah = [&](size_t n) { f16* q = hbuf + ho; ho += n; return q; };
    f16* z_h   = ah((size_t)NB * ND2);
    f16* z_l   = ah((size_t)NB * ND2);
    f16* p_h   = ah((size_t)NB * ND2);
    f16* p_l   = ah((size_t)NB * ND2);
    f16* q_h   = ah((size_t)NB * ND2);
    f16* q_l   = ah((size_t)NB * ND2);
    f16* k_h   = ah((size_t)NB * ND2);
    f16* k_l   = ah((size_t)NB * ND2);
    f16* vT_h  = ah((size_t)NB * ND2);
    f16* vT_l  = ah((size_t)NB * ND2);
    f16* A_h   = ah((size_t)NB * NB);
    f16* A_l   = ah((size_t)NB * NB);
    f16* cf_h  = ah((size_t)NB * ND2);
    f16* cf_l  = ah((size_t)NB * ND2);
    f16* zw_h  = ah((size_t)NB * ND2);
    f16* zw_l  = ah((size_t)NB * ND2);
    f16* W1_h  = ah((size_t)ND2 * ND2);
    f16* W1_l  = ah((size_t)ND2 * ND2);
    f16* Wq_h  = ah((size_t)3 * ND2 * ND2);
    f16* Wq_l  = ah((size_t)3 * ND2 * ND2);
    f16* cb_h  = ah((size_t)NK * ND2);
    f16* cb_l  = ah((size_t)NK * ND2);
    f16* dW_h  = ah((size_t)NV * ND2);

    hipMemsetAsync(memb, 0, (size_t)NB * NSTACK * ND2 * sizeof(float), stream);
    hipMemsetAsync(zw, 0, (size_t)NB * ND2 * sizeof(float), stream);
    k_init<<<4, 256, 0, stream>>>(ptrb, remainb, scal);
    k_embed<<<NB, 256, 0, stream>>>(input_ids, emb_mag, emb_phase, z_h, z_l);
    k_cbnorm<<<NK, 256, 0, stream>>>(codebook, cbn);
    k_buildW1<<<(ND2 * ND2) / 256, 256, 0, stream>>>(lin_r, lin_i, W1_h, W1_l);
    k_buildWqkv<<<(3 * ND2 * ND2) / 256, 256, 0, stream>>>(q_r, q_i, k_r, k_i, v_r, v_i, Wq_h, Wq_l);
    k_splitcb<<<(NK * ND2) / 256, 256, 0, stream>>>(codebook, cb_h, cb_l);
    k_split_h<<<2048, 256, 0, stream>>>(dec_W, dW_h, (size_t)NV * ND2);

    const float att_scale = 0.044194173824159216f;  // 1/sqrt(512)
    for (int step = 0; step < NSTEPS; ++step) {
        k_sgemm4<0><<<dim3(16, 16), 512, 0, stream>>>(z_h, z_l, W1_h, W1_l, scr,
            nullptr, nullptr, nullptr, nullptr, nullptr, nullptr, ND2, ND2, 1.f);
        k_cnorm<<<NB, 256, 0, stream>>>(scr, p_h, p_l, norm_scale, norm_shift, mod_bias);
        k_sgemm4<2><<<dim3(48, 16), 512, 0, stream>>>(p_h, p_l, Wq_h, Wq_l, nullptr,
            q_h, q_l, k_h, k_l, vT_h, vT_l, 3 * ND2, ND2, 1.f);
        k_sgemm4<0><<<dim3(16, 16), 512, 0, stream>>>(q_h, q_l, k_h, k_l, scr,
            nullptr, nullptr, nullptr, nullptr, nullptr, nullptr, NB, ND2, att_scale);
        k_softmax<<<NB, 256, 0, stream>>>(scr, A_h, A_l);
        k_sgemm4<0><<<dim3(16, 16), 512, 0, stream>>>(A_h, A_l, vT_h, vT_l, scr,
            nullptr, nullptr, nullptr, nullptr, nullptr, nullptr, ND2, NB, 9.765625e-4f);
        k_stack<<<NB, 256, 0, stream>>>(scr, halt_W, halt_b, ctrl_W, ctrl_b, ptrb, memb, haltb, cf, cf_h, cf_l);
        k_sgemm4<0><<<dim3(16, 16), 512, 0, stream>>>(cf_h, cf_l, cb_h, cb_l, scr,
            nullptr, nullptr, nullptr, nullptr, nullptr, nullptr, NK, ND2, 1.f);
        k_vqstep<<<NB, 256, 0, stream>>>(scr, cf, codebook, cbn, cb_h, cb_l, adjacency, haltb, remainb,
                                         z_h, z_l, zw, prev, scal, step, step == NSTEPS - 1 ? 1 : 0);
    }
    k_split1<<<(NB * ND2) / 256, 256, 0, stream>>>(zw, zw_h, zw_l);
    k_dgemm4<<<2000, 512, 0, stream>>>(zw_h, dW_h, out, dec_b);
    k_aux<<<1, 1, 0, stream>>>(scal, out + (size_t)NB * NV);
}

// Round 7
// 1805.055 us; speedup vs baseline: 1.2758x; 1.2758x over previous
//
#include <hip/hip_runtime.h>
#include <math.h>

#define NB 1024
#define ND 512
#define ND2 1024
#define NSTEPS 8
#define NSTACK 16
#define NK 1024
#define NV 32000
#define FEPS 1e-6f

typedef _Float16 f16;
typedef f16 f16x8 __attribute__((ext_vector_type(8)));
typedef f16 f16x4 __attribute__((ext_vector_type(4)));
typedef float f32x4 __attribute__((ext_vector_type(4)));

// LDS layout: row stride 32 halfs (64B, pad-free), 16B-chunk swizzle
// phys_chunk = chunk ^ ((row>>1)&3). Wave-level fragment reads and staging
// writes each cover a contiguous 1KB bijectively -> <=2-way bank aliasing (free).
__device__ __forceinline__ int swz(int row, int chunk) {
    return row * 32 + ((chunk ^ ((row >> 1) & 3)) * 8);
}

// ---------------- block reduction helpers (blockDim == 256) ----------------
__device__ __forceinline__ float blk_sum(float v, float* red) {
    int t = threadIdx.x;
    red[t] = v; __syncthreads();
    for (int s = 128; s > 0; s >>= 1) {
        if (t < s) red[t] += red[t + s];
        __syncthreads();
    }
    float r = red[0]; __syncthreads();
    return r;
}

__device__ __forceinline__ float blk_max(float v, float* red) {
    int t = threadIdx.x;
    red[t] = v; __syncthreads();
    for (int s = 128; s > 0; s >>= 1) {
        if (t < s) red[t] = fmaxf(red[t], red[t + s]);
        __syncthreads();
    }
    float r = red[0]; __syncthreads();
    return r;
}

__device__ __forceinline__ void split_write(float v, f16* oh, f16* ol, size_t idx) {
    f16 h = (f16)v;
    oh[idx] = h;
    ol[idx] = (f16)((v - (float)h) * 1024.f);
}

// ---------------- init ----------------
__global__ __launch_bounds__(256)
void k_init(float* ptrb, float* remainb, float* scal) {
    int i = blockIdx.x * 256 + threadIdx.x;
    if (i < NB) {
        remainb[i] = 1.f;
        for (int s = 0; s < NSTACK; ++s) ptrb[i * NSTACK + s] = (s == 0) ? 1.f : 0.f;
    }
    if (i < 8) scal[i] = 0.f;
}

__global__ __launch_bounds__(256)
void k_embed(const int* __restrict__ ids, const float* __restrict__ mag,
             const float* __restrict__ ph, f16* __restrict__ zh, f16* __restrict__ zl) {
    int b = blockIdx.x;
    int id = ids[b];
    for (int d = threadIdx.x; d < ND; d += 256) {
        float m = mag[(size_t)id * ND + d];
        float p = ph[(size_t)id * ND + d];
        split_write(m * cosf(p), zh, zl, (size_t)b * ND2 + d);
        split_write(m * sinf(p), zh, zl, (size_t)b * ND2 + ND + d);
    }
}

__global__ __launch_bounds__(256)
void k_cbnorm(const float* __restrict__ cb, float* __restrict__ cbn) {
    __shared__ float red[256];
    int k = blockIdx.x;
    float s = 0.f;
    for (int c = threadIdx.x; c < ND2; c += 256) {
        float v = cb[(size_t)k * ND2 + c];
        s += v * v;
    }
    float tot = blk_sum(s, red);
    if (threadIdx.x == 0) cbn[k] = tot;
}

// ---------------- weight builders ----------------
__global__ __launch_bounds__(256)
void k_buildW1(const float* __restrict__ lr, const float* __restrict__ li,
               f16* __restrict__ oh, f16* __restrict__ ol) {
    int idx = blockIdx.x * 256 + threadIdx.x;
    int n = idx >> 10, k = idx & 1023;
    float v;
    if (n < 512) v = (k < 512) ? lr[n * 512 + k] : -li[n * 512 + (k - 512)];
    else { int n2 = n - 512; v = (k < 512) ? li[n2 * 512 + k] : lr[n2 * 512 + (k - 512)]; }
    split_write(v, oh, ol, idx);
}

__global__ __launch_bounds__(256)
void k_buildWqkv(const float* __restrict__ qr, const float* __restrict__ qi,
                 const float* __restrict__ kr, const float* __restrict__ ki,
                 const float* __restrict__ vr, const float* __restrict__ vi,
                 f16* __restrict__ oh, f16* __restrict__ ol) {
    int idx = blockIdx.x * 256 + threadIdx.x;
    int n = idx >> 10, k = idx & 1023;
    int g = n >> 10, n1 = n & 1023;
    const float* Wr = (g == 0) ? qr : (g == 1) ? kr : vr;
    const float* Wi = (g == 0) ? qi : (g == 1) ? ki : vi;
    float v;
    if (n1 < 512) v = (k < 512) ? Wr[n1 * 512 + k] : -Wi[n1 * 512 + (k - 512)];
    else { int n2 = n1 - 512; v = (k < 512) ? Wi[n2 * 512 + k] : Wr[n2 * 512 + (k - 512)]; }
    split_write(v, oh, ol, idx);
}

__global__ __launch_bounds__(256)
void k_splitcb(const float* __restrict__ in, f16* __restrict__ oh, f16* __restrict__ ol) {
    int idx = blockIdx.x * 256 + threadIdx.x;
    split_write(in[idx], oh, ol, idx);
}

__global__ __launch_bounds__(256)
void k_split_h(const float* __restrict__ in, f16* __restrict__ oh, size_t n) {
    size_t i = (size_t)blockIdx.x * 256 + threadIdx.x;
    size_t st = (size_t)gridDim.x * 256;
    for (; i < n; i += st) oh[i] = (f16)in[i];
}

__global__ __launch_bounds__(256)
void k_split1(const float* __restrict__ in, f16* __restrict__ oh, f16* __restrict__ ol) {
    int idx = blockIdx.x * 256 + threadIdx.x;
    split_write(in[idx], oh, ol, idx);
}

// ---------------- in-loop fp16(x2-split) MFMA NT GEMM, in-block split-K-2 ----
// C[M,N] = alpha * (A .* B^T). value = hi + lo/1024, 3-product compensated.
// Block: 64x64 out, 512 thr = 2 K-groups x 4 waves, wave tile 32x32.
// LDS conflict-free swizzle, double-buffered (1 barrier/iter), reg prefetch.
template<int EPI>
__global__ __launch_bounds__(512, 4)
void k_sgemm5(const f16* __restrict__ Ah, const f16* __restrict__ Al,
              const f16* __restrict__ Bh, const f16* __restrict__ Bl,
              float* __restrict__ Cf,
              f16* __restrict__ qh, f16* __restrict__ ql,
              f16* __restrict__ kh, f16* __restrict__ kl,
              f16* __restrict__ vTh, f16* __restrict__ vTl,
              int N, int K, float alpha) {
    __shared__ f16 lds[2][2][4][64 * 32];   // [buf][group][Ah,Al,Bh,Bl]  (64 KB)
    const int tid = threadIdx.x;
    const int g = tid >> 8;
    const int gt = tid & 255;
    const int srow = gt >> 2, scb = gt & 3;
    const int soff = swz(srow, scb);
    const int lane = tid & 63;
    const int q = (tid >> 6) & 3;
    const int qr = (q >> 1) * 32, qc = (q & 1) * 32;
    const int fr = lane & 15, cbk = lane >> 4;
    const int m0 = blockIdx.y * 64, n0 = blockIdx.x * 64;
    const int kbase = g * (K >> 1);
    const int iters = K >> 6;

    const f16* pA  = Ah + (size_t)(m0 + srow) * K + kbase + scb * 8;
    const f16* pAl_ = Al + (size_t)(m0 + srow) * K + kbase + scb * 8;
    const f16* pB  = Bh + (size_t)(n0 + srow) * K + kbase + scb * 8;
    const f16* pBl_ = Bl + (size_t)(n0 + srow) * K + kbase + scb * 8;

    f32x4 z4 = {0.f, 0.f, 0.f, 0.f};
    f32x4 acc0[2][2] = {{z4, z4}, {z4, z4}};
    f32x4 acc1[2][2] = {{z4, z4}, {z4, z4}};

    // prologue: stage iter0 -> buf0, prefetch iter1 into regs
    f16x8 rA  = *(const f16x8*)pA;
    f16x8 rAl = *(const f16x8*)pAl_;
    f16x8 rB  = *(const f16x8*)pB;
    f16x8 rBl = *(const f16x8*)pBl_;
    *(f16x8*)&lds[0][g][0][soff] = rA;
    *(f16x8*)&lds[0][g][1][soff] = rAl;
    *(f16x8*)&lds[0][g][2][soff] = rB;
    *(f16x8*)&lds[0][g][3][soff] = rBl;
    if (iters > 1) {
        rA  = *(const f16x8*)(pA + 32);
        rAl = *(const f16x8*)(pAl_ + 32);
        rB  = *(const f16x8*)(pB + 32);
        rBl = *(const f16x8*)(pBl_ + 32);
    }
    __syncthreads();

    for (int it = 0; it < iters; ++it) {
        const int cur = it & 1;
        f16x8 ah[2], al[2], bh[2], bl[2];
        #pragma unroll
        for (int i = 0; i < 2; ++i) {
            int ra = qr + i * 16 + fr;
            int oa = swz(ra, cbk);
            ah[i] = *(const f16x8*)&lds[cur][g][0][oa];
            al[i] = *(const f16x8*)&lds[cur][g][1][oa];
            int rb = qc + i * 16 + fr;
            int ob = swz(rb, cbk);
            bh[i] = *(const f16x8*)&lds[cur][g][2][ob];
            bl[i] = *(const f16x8*)&lds[cur][g][3][ob];
        }
        if (it + 1 < iters) {
            *(f16x8*)&lds[cur ^ 1][g][0][soff] = rA;
            *(f16x8*)&lds[cur ^ 1][g][1][soff] = rAl;
            *(f16x8*)&lds[cur ^ 1][g][2][soff] = rB;
            *(f16x8*)&lds[cur ^ 1][g][3][soff] = rBl;
            if (it + 2 < iters) {
                int ko = (it + 2) * 32;
                rA  = *(const f16x8*)(pA + ko);
                rAl = *(const f16x8*)(pAl_ + ko);
                rB  = *(const f16x8*)(pB + ko);
                rBl = *(const f16x8*)(pBl_ + ko);
            }
        }
        #pragma unroll
        for (int i = 0; i < 2; ++i)
            #pragma unroll
            for (int j = 0; j < 2; ++j) {
                acc0[i][j] = __builtin_amdgcn_mfma_f32_16x16x32_f16(ah[i], bh[j], acc0[i][j], 0, 0, 0);
                acc1[i][j] = __builtin_amdgcn_mfma_f32_16x16x32_f16(ah[i], bl[j], acc1[i][j], 0, 0, 0);
                acc1[i][j] = __builtin_amdgcn_mfma_f32_16x16x32_f16(al[i], bh[j], acc1[i][j], 0, 0, 0);
            }
        __syncthreads();
    }

    float val[2][2][4];
    #pragma unroll
    for (int i = 0; i < 2; ++i)
        #pragma unroll
        for (int j = 0; j < 2; ++j)
            #pragma unroll
            for (int jj = 0; jj < 4; ++jj)
                val[i][j][jj] = acc0[i][j][jj] + acc1[i][j][jj] * 9.765625e-4f;

    float* red = (float*)&lds[0][0][0][0];   // 4 waves x 32x33 f32 = 16.9 KB
    if (g == 1) {
        #pragma unroll
        for (int i = 0; i < 2; ++i)
            #pragma unroll
            for (int j = 0; j < 2; ++j) {
                int r = i * 16 + (lane >> 4) * 4, c = j * 16 + (lane & 15);
                #pragma unroll
                for (int jj = 0; jj < 4; ++jj)
                    red[q * 1056 + (r + jj) * 33 + c] = val[i][j][jj];
            }
    }
    __syncthreads();
    if (g == 0) {
        #pragma unroll
        for (int i = 0; i < 2; ++i)
            #pragma unroll
            for (int j = 0; j < 2; ++j) {
                int r = i * 16 + (lane >> 4) * 4, c = j * 16 + (lane & 15);
                #pragma unroll
                for (int jj = 0; jj < 4; ++jj)
                    val[i][j][jj] += red[q * 1056 + (r + jj) * 33 + c];
                int orow = m0 + qr + r;
                int ocol = n0 + qc + c;
                if constexpr (EPI == 0) {
                    #pragma unroll
                    for (int jj = 0; jj < 4; ++jj)
                        Cf[(size_t)(orow + jj) * N + ocol] = alpha * val[i][j][jj];
                } else {
                    int sec = ocol >> 10, lc = ocol & 1023;
                    if (sec == 0) {
                        #pragma unroll
                        for (int jj = 0; jj < 4; ++jj)
                            split_write(val[i][j][jj], qh, ql, (size_t)(orow + jj) * ND2 + lc);
                    } else if (sec == 1) {
                        #pragma unroll
                        for (int jj = 0; jj < 4; ++jj)
                            split_write(val[i][j][jj], kh, kl, (size_t)(orow + jj) * ND2 + lc);
                    } else {
                        f16x4 th, tl;
                        #pragma unroll
                        for (int jj = 0; jj < 4; ++jj) {
                            float v = val[i][j][jj];
                            f16 h = (f16)v;
                            th[jj] = h;
                            tl[jj] = (f16)((v - (float)h) * 1024.f);
                        }
                        *(f16x4*)&vTh[(size_t)lc * ND2 + orow] = th;
                        *(f16x4*)&vTl[(size_t)lc * ND2 + orow] = tl;
                    }
                }
            }
    }
}

// ---------------- decoder GEMM: C = A .* B^T + bias, hi-only fp16 ----------
// BM=256, BN=128, BK=32, 512 thr = 8 waves (4M x 2N), wave tile 64x64.
// B in LDS; conflict-free swizzle; double-buffered; XCD-chunked block swizzle.
__global__ __launch_bounds__(512, 4)
void k_dgemm5(const f16* __restrict__ A, const f16* __restrict__ B,
              float* __restrict__ C, const float* __restrict__ bias) {
    __shared__ f16 sA[2][256 * 32];   // 16 KB x2
    __shared__ f16 sB[2][128 * 32];   //  8 KB x2
    const int bid = blockIdx.x;               // 0..999 (bijective: 1000 = 8*125)
    const int l2 = (bid & 7) * 125 + (bid >> 3);
    const int m0 = (l2 & 3) * 256;
    const int n0 = (l2 >> 2) * 128;
    const int tid = threadIdx.x;
    const int lane = tid & 63, w = tid >> 6;
    const int wr = (w >> 1) * 64, wc = (w & 1) * 64;
    const int fr = lane & 15, cbk = lane >> 4;
    const int K = ND2;
    const int ra = tid >> 1, ca0 = (tid & 1) * 2;
    const int rb = tid >> 2, cb0 = tid & 3;
    const int oa0 = swz(ra, ca0), oa1 = swz(ra, ca0 + 1), ob0 = swz(rb, cb0);

    const f16* pA = A + (size_t)(m0 + ra) * K + ca0 * 8;
    const f16* pB = B + (size_t)(n0 + rb) * K + cb0 * 8;

    f32x4 z4 = {0.f, 0.f, 0.f, 0.f};
    f32x4 acc[4][4];
    #pragma unroll
    for (int i = 0; i < 4; ++i)
        #pragma unroll
        for (int j = 0; j < 4; ++j) acc[i][j] = z4;

    f16x8 rA0 = *(const f16x8*)pA;
    f16x8 rA1 = *(const f16x8*)(pA + 8);
    f16x8 rB0 = *(const f16x8*)pB;
    *(f16x8*)&sA[0][oa0] = rA0;
    *(f16x8*)&sA[0][oa1] = rA1;
    *(f16x8*)&sB[0][ob0] = rB0;
    rA0 = *(const f16x8*)(pA + 32);
    rA1 = *(const f16x8*)(pA + 40);
    rB0 = *(const f16x8*)(pB + 32);
    __syncthreads();

    for (int it = 0; it < 32; ++it) {
        const int cur = it & 1;
        f16x8 a[4], b[4];
        #pragma unroll
        for (int i = 0; i < 4; ++i) {
            int rra = wr + i * 16 + fr;
            a[i] = *(const f16x8*)&sA[cur][swz(rra, cbk)];
        }
        #pragma unroll
        for (int j = 0; j < 4; ++j) {
            int rrb = wc + j * 16 + fr;
            b[j] = *(const f16x8*)&sB[cur][swz(rrb, cbk)];
        }
        if (it + 1 < 32) {
            *(f16x8*)&sA[cur ^ 1][oa0] = rA0;
            *(f16x8*)&sA[cur ^ 1][oa1] = rA1;
            *(f16x8*)&sB[cur ^ 1][ob0] = rB0;
            if (it + 2 < 32) {
                int ko = (it + 2) * 32;
                rA0 = *(const f16x8*)(pA + ko);
                rA1 = *(const f16x8*)(pA + ko + 8);
                rB0 = *(const f16x8*)(pB + ko);
            }
        }
        #pragma unroll
        for (int i = 0; i < 4; ++i)
            #pragma unroll
            for (int j = 0; j < 4; ++j)
                acc[i][j] = __builtin_amdgcn_mfma_f32_16x16x32_f16(a[i], b[j], acc[i][j], 0, 0, 0);
        __syncthreads();
    }
    #pragma unroll
    for (int i = 0; i < 4; ++i)
        #pragma unroll
        for (int j = 0; j < 4; ++j) {
            int orow = m0 + wr + i * 16 + (lane >> 4) * 4;
            int ocol = n0 + wc + j * 16 + (lane & 15);
            float bv = bias[ocol];
            #pragma unroll
            for (int jj = 0; jj < 4; ++jj)
                C[(size_t)(orow + jj) * NV + ocol] = acc[i][j][jj] + bv;
        }
}

// ---------------- cnorm + modrelu: read f32 p rows, write split fp16 -------
__global__ __launch_bounds__(256)
void k_cnorm(const float* __restrict__ p, f16* __restrict__ ph, f16* __restrict__ pl,
             const float* __restrict__ scale, const float* __restrict__ shift,
             const float* __restrict__ mbias) {
    __shared__ float red[256];
    int b = blockIdx.x, t = threadIdx.x;
    float xr[2], xi[2], hv[2];
    float lsum = 0.f;
    #pragma unroll
    for (int l = 0; l < 2; ++l) {
        int d = t + l * 256;
        float a = p[(size_t)b * ND2 + d], c = p[(size_t)b * ND2 + ND + d];
        xr[l] = a; xi[l] = c;
        float h = sqrtf(a * a + c * c);
        hv[l] = h;
        lsum += h + FEPS;
    }
    float mean = blk_sum(lsum, red) * (1.f / ND);
    float lvar = 0.f;
    #pragma unroll
    for (int l = 0; l < 2; ++l) {
        float dv = (hv[l] + FEPS) - mean;
        lvar += dv * dv;
    }
    float var = blk_sum(lvar, red) * (1.f / (ND - 1));
    float istd = 1.f / sqrtf(var + FEPS);
    #pragma unroll
    for (int l = 0; l < 2; ++l) {
        int d = t + l * 256;
        float nm = ((hv[l] + FEPS) - mean) * istd * scale[d] + shift[d];
        float cc, ss;
        if (hv[l] > 0.f) { cc = xr[l] / hv[l]; ss = xi[l] / hv[l]; }
        else             { cc = 1.f; ss = 0.f; }
        float vr_ = nm * cc, vi_ = nm * ss;
        float n = sqrtf(vr_ * vr_ + vi_ * vi_) + FEPS;
        float aarg = n + mbias[d];
        float sg = (aarg > 0.f ? aarg : 0.f) / n;
        split_write(vr_ * sg, ph, pl, (size_t)b * ND2 + d);
        split_write(vi_ * sg, ph, pl, (size_t)b * ND2 + ND + d);
    }
}

// ---------------- row softmax over 1024, writes scaled (x1024) split fp16
__global__ __launch_bounds__(256)
void k_softmax(const float* __restrict__ S, f16* __restrict__ Ah, f16* __restrict__ Al) {
    __shared__ float red[256];
    int row = blockIdx.x, t = threadIdx.x;
    float v[4];
    float lm = -INFINITY;
    #pragma unroll
    for (int l = 0; l < 4; ++l) {
        v[l] = S[(size_t)row * NB + t + l * 256];
        lm = fmaxf(lm, v[l]);
    }
    float mx = blk_max(lm, red);
    float ls = 0.f;
    #pragma unroll
    for (int l = 0; l < 4; ++l) { v[l] = expf(v[l] - mx); ls += v[l]; }
    float tot = blk_sum(ls, red);
    float inv = 1024.f / tot;
    #pragma unroll
    for (int l = 0; l < 4; ++l)
        split_write(v[l] * inv, Ah, Al, (size_t)row * NB + t + l * 256);
}

// ---------------- halt/ctrl/stack/read/cf
__global__ __launch_bounds__(256)
void k_stack(const float* __restrict__ zf, const float* __restrict__ hW,
             const float* __restrict__ hB, const float* __restrict__ cW,
             const float* __restrict__ cB, float* __restrict__ ptrb,
             float* __restrict__ memb, float* __restrict__ haltb,
             float* __restrict__ cf, f16* __restrict__ cfh, f16* __restrict__ cfl) {
    __shared__ float zfs[ND2];
    __shared__ float red[256];
    __shared__ float pt[NSTACK], npv[NSTACK], wmv[NSTACK];
    __shared__ float snorm;
    int b = blockIdx.x, t = threadIdx.x;
    for (int c = t; c < ND2; c += 256) zfs[c] = zf[(size_t)b * ND2 + c];
    __syncthreads();
    float dh = 0, d0 = 0, d1 = 0, d2 = 0;
    for (int c = t; c < ND2; c += 256) {
        float z = zfs[c];
        dh += z * hW[c];
        d0 += z * cW[c];
        d1 += z * cW[ND2 + c];
        d2 += z * cW[2 * ND2 + c];
    }
    dh = blk_sum(dh, red);
    d0 = blk_sum(d0, red);
    d1 = blk_sum(d1, red);
    d2 = blk_sum(d2, red);
    float h = 1.f / (1.f + expf(-(dh + hB[0])));
    float l0 = d0 + cB[0], l1 = d1 + cB[1], l2 = d2 + cB[2];
    float mx = fmaxf(l0, fmaxf(l1, l2));
    float e0 = expf(l0 - mx), e1 = expf(l1 - mx), e2 = expf(l2 - mx);
    float es = e0 + e1 + e2;
    float push = e0 / es, pop = e1 / es, noop = e2 / es;
    if (t < NSTACK) pt[t] = ptrb[b * NSTACK + t];
    __syncthreads();
    if (t < NSTACK) {
        float up = pt[(t + NSTACK - 1) & 15];
        float dn = pt[(t + 1) & 15];
        npv[t] = push * up + pop * dn + noop * pt[t];
        wmv[t] = push * up;
    }
    __syncthreads();
    if (t == 0) {
        float s = 0.f;
        for (int j = 0; j < NSTACK; ++j) s += npv[j];
        snorm = 1.f / (s + FEPS);
    }
    __syncthreads();
    if (t < NSTACK) {
        npv[t] *= snorm;
        ptrb[b * NSTACK + t] = npv[t];
    }
    __syncthreads();
    for (int c = t; c < ND2; c += 256) {
        float z = zfs[c];
        float rd = 0.f;
        #pragma unroll
        for (int s = 0; s < NSTACK; ++s) {
            size_t off = ((size_t)b * NSTACK + s) * ND2 + c;
            float m = memb[off];
            m = wmv[s] * z + m * (1.f - wmv[s]);
            memb[off] = m;
            rd += m * npv[s];
        }
        float v = z + rd;
        cf[(size_t)b * ND2 + c] = v;
        split_write(v, cfh, cfl, (size_t)b * ND2 + c);
    }
    if (t == 0) haltb[b] = h;
}

// ---------------- VQ argmin + losses + state update
__global__ __launch_bounds__(256)
void k_vqstep(const float* __restrict__ G, const float* __restrict__ cf,
              const float* __restrict__ cb, const float* __restrict__ cbn,
              const f16* __restrict__ cbh, const f16* __restrict__ cbl,
              const float* __restrict__ adj, const float* __restrict__ haltb,
              float* __restrict__ remainb, f16* __restrict__ zh, f16* __restrict__ zl,
              float* __restrict__ zw, int* __restrict__ prev, float* __restrict__ scal,
              int step, int islast) {
    __shared__ float sval[256];
    __shared__ int sidx[256];
    __shared__ float red[256];
    int b = blockIdx.x, t = threadIdx.x;
    float bv = INFINITY; int bi = NK;
    for (int k = t; k < NK; k += 256) {
        float v = cbn[k] - 2.f * G[(size_t)b * NK + k];
        if (v < bv) { bv = v; bi = k; }
    }
    sval[t] = bv; sidx[t] = bi;
    __syncthreads();
    for (int s = 128; s > 0; s >>= 1) {
        if (t < s) {
            float ov = sval[t + s]; int oi = sidx[t + s];
            if (ov < sval[t] || (ov == sval[t] && oi < sidx[t])) { sval[t] = ov; sidx[t] = oi; }
        }
        __syncthreads();
    }
    int sym = sidx[0];
    float sd = 0.f;
    for (int c = t; c < ND2; c += 256) {
        float dd = cb[(size_t)sym * ND2 + c] - cf[(size_t)b * ND2 + c];
        sd += dd * dd;
    }
    float sdt = blk_sum(sd, red);
    float contrib = 0.f;
    if (step > 0) {
        int pv = prev[b];
        float lm = -INFINITY;
        for (int c = t; c < NK; c += 256) lm = fmaxf(lm, adj[(size_t)pv * NK + c]);
        float mxa = blk_max(lm, red);
        float le = 0.f;
        for (int c = t; c < NK; c += 256) le += expf(adj[(size_t)pv * NK + c] - mxa);
        float se = blk_sum(le, red);
        contrib = (mxa + logf(se)) - adj[(size_t)pv * NK + sym];
    }
    float hb = haltb[b];
    float rm = remainb[b];
    float w = islast ? rm : hb * rm;
    for (int c = t; c < ND2; c += 256) {
        zw[(size_t)b * ND2 + c] += w * cb[(size_t)sym * ND2 + c];
        zh[(size_t)b * ND2 + c] = cbh[(size_t)sym * ND2 + c];
        zl[(size_t)b * ND2 + c] = cbl[(size_t)sym * ND2 + c];
    }
    if (t == 0) {
        float nrm = rm * (1.f - hb);
        remainb[b] = nrm;
        atomicAdd(&scal[0], sdt);
        if (step > 0) atomicAdd(&scal[1], contrib);
        atomicAdd(&scal[2], nrm);
        prev[b] = sym;
    }
}

__global__ void k_aux(const float* __restrict__ scal, float* __restrict__ out) {
    out[0] = 1.25f * scal[0] / (1024.f * 1024.f)
           + 0.005f * (scal[1] / 1024.f)
           + 0.0001f * (scal[2] / 1024.f);
}

// ---------------- launch ----------------
extern "C" void kernel_launch(void* const* d_in, const int* in_sizes, int n_in,
                              void* d_out, int out_size, void* d_ws, size_t ws_size,
                              hipStream_t stream) {
    const int*   input_ids  = (const int*)  d_in[0];
    const float* emb_mag    = (const float*)d_in[1];
    const float* emb_phase  = (const float*)d_in[2];
    const float* lin_r      = (const float*)d_in[3];
    const float* lin_i      = (const float*)d_in[4];
    const float* norm_scale = (const float*)d_in[5];
    const float* norm_shift = (const float*)d_in[6];
    const float* mod_bias   = (const float*)d_in[7];
    const float* halt_W     = (const float*)d_in[8];
    const float* halt_b     = (const float*)d_in[9];
    const float* ctrl_W     = (const float*)d_in[10];
    const float* ctrl_b     = (const float*)d_in[11];
    const float* q_r        = (const float*)d_in[12];
    const float* q_i        = (const float*)d_in[13];
    const float* k_r        = (const float*)d_in[14];
    const float* k_i        = (const float*)d_in[15];
    const float* v_r        = (const float*)d_in[16];
    const float* v_i        = (const float*)d_in[17];
    const float* codebook   = (const float*)d_in[18];
    const float* adjacency  = (const float*)d_in[19];
    const float* dec_W      = (const float*)d_in[20];
    const float* dec_b      = (const float*)d_in[21];
    float* out = (float*)d_out;

    // ---- workspace carve-up (f32 region, then f16 region) ----
    float* fb = (float*)d_ws;
    size_t o = 0;
    auto af = [&](size_t n) { float* p = fb + o; o += n; return p; };
    float* scr      = af((size_t)NB * ND2);   // p / S / zf / G (time-aliased)
    float* cf       = af((size_t)NB * ND2);
    float* memb     = af((size_t)NB * NSTACK * ND2);
    float* zw       = af((size_t)NB * ND2);
    float* ptrb     = af((size_t)NB * NSTACK);
    float* haltb    = af(NB);
    float* remainb  = af(NB);
    float* cbn      = af(NK);
    int*   prev     = (int*)af(NB);
    float* scal     = af(8);

    f16* hbuf = (f16*)(fb + o);
    size_t ho = 0;
    auto ah = [&](size_t n) { f16* q = hbuf + ho; ho += n; return q; };
    f16* z_h   = ah((size_t)NB * ND2);
    f16* z_l   = ah((size_t)NB * ND2);
    f16* p_h   = ah((size_t)NB * ND2);
    f16* p_l   = ah((size_t)NB * ND2);
    f16* q_h   = ah((size_t)NB * ND2);
    f16* q_l   = ah((size_t)NB * ND2);
    f16* k_h   = ah((size_t)NB * ND2);
    f16* k_l   = ah((size_t)NB * ND2);
    f16* vT_h  = ah((size_t)NB * ND2);
    f16* vT_l  = ah((size_t)NB * ND2);
    f16* A_h   = ah((size_t)NB * NB);
    f16* A_l   = ah((size_t)NB * NB);
    f16* cf_h  = ah((size_t)NB * ND2);
    f16* cf_l  = ah((size_t)NB * ND2);
    f16* zw_h  = ah((size_t)NB * ND2);
    f16* zw_l  = ah((size_t)NB * ND2);
    f16* W1_h  = ah((size_t)ND2 * ND2);
    f16* W1_l  = ah((size_t)ND2 * ND2);
    f16* Wq_h  = ah((size_t)3 * ND2 * ND2);
    f16* Wq_l  = ah((size_t)3 * ND2 * ND2);
    f16* cb_h  = ah((size_t)NK * ND2);
    f16* cb_l  = ah((size_t)NK * ND2);
    f16* dW_h  = ah((size_t)NV * ND2);

    hipMemsetAsync(memb, 0, (size_t)NB * NSTACK * ND2 * sizeof(float), stream);
    hipMemsetAsync(zw, 0, (size_t)NB * ND2 * sizeof(float), stream);
    k_init<<<4, 256, 0, stream>>>(ptrb, remainb, scal);
    k_embed<<<NB, 256, 0, stream>>>(input_ids, emb_mag, emb_phase, z_h, z_l);
    k_cbnorm<<<NK, 256, 0, stream>>>(codebook, cbn);
    k_buildW1<<<(ND2 * ND2) / 256, 256, 0, stream>>>(lin_r, lin_i, W1_h, W1_l);
    k_buildWqkv<<<(3 * ND2 * ND2) / 256, 256, 0, stream>>>(q_r, q_i, k_r, k_i, v_r, v_i, Wq_h, Wq_l);
    k_splitcb<<<(NK * ND2) / 256, 256, 0, stream>>>(codebook, cb_h, cb_l);
    k_split_h<<<2048, 256, 0, stream>>>(dec_W, dW_h, (size_t)NV * ND2);

    const float att_scale = 0.044194173824159216f;  // 1/sqrt(512)
    for (int step = 0; step < NSTEPS; ++step) {
        k_sgemm5<0><<<dim3(16, 16), 512, 0, stream>>>(z_h, z_l, W1_h, W1_l, scr,
            nullptr, nullptr, nullptr, nullptr, nullptr, nullptr, ND2, ND2, 1.f);
        k_cnorm<<<NB, 256, 0, stream>>>(scr, p_h, p_l, norm_scale, norm_shift, mod_bias);
        k_sgemm5<2><<<dim3(48, 16), 512, 0, stream>>>(p_h, p_l, Wq_h, Wq_l, nullptr,
            q_h, q_l, k_h, k_l, vT_h, vT_l, 3 * ND2, ND2, 1.f);
        k_sgemm5<0><<<dim3(16, 16), 512, 0, stream>>>(q_h, q_l, k_h, k_l, scr,
            nullptr, nullptr, nullptr, nullptr, nullptr, nullptr, NB, ND2, att_scale);
        k_softmax<<<NB, 256, 0, stream>>>(scr, A_h, A_l);
        k_sgemm5<0><<<dim3(16, 16), 512, 0, stream>>>(A_h, A_l, vT_h, vT_l, scr,
            nullptr, nullptr, nullptr, nullptr, nullptr, nullptr, ND2, NB, 9.765625e-4f);
        k_stack<<<NB, 256, 0, stream>>>(scr, halt_W, halt_b, ctrl_W, ctrl_b, ptrb, memb, haltb, cf, cf_h, cf_l);
        k_sgemm5<0><<<dim3(16, 16), 512, 0, stream>>>(cf_h, cf_l, cb_h, cb_l, scr,
            nullptr, nullptr, nullptr, nullptr, nullptr, nullptr, NK, ND2, 1.f);
        k_vqstep<<<NB, 256, 0, stream>>>(scr, cf, codebook, cbn, cb_h, cb_l, adjacency, haltb, remainb,
                                         z_h, z_l, zw, prev, scal, step, step == NSTEPS - 1 ? 1 : 0);
    }
    k_split1<<<(NB * ND2) / 256, 256, 0, stream>>>(zw, zw_h, zw_l);
    k_dgemm5<<<1000, 512, 0, stream>>>(zw_h, dW_h, out, dec_b);
    k_aux<<<1, 1, 0, stream>>>(scal, out + (size_t)NB * NV);
}